// Round 6
// baseline (620.265 us; speedup 1.0000x reference)
//
#include <hip/hip_runtime.h>

#define NSMP 8192
#define INW  8712   // input row stride (floats)
#define OUTW 8448   // output row stride (floats)
#define AOFF 512    // column offset of A block inside input
#define DO   256    // DOUT

typedef __attribute__((ext_vector_type(4)))  float f32x4;
typedef __attribute__((ext_vector_type(8)))  short short8;
typedef __attribute__((ext_vector_type(16))) float floatx16;

typedef __attribute__((address_space(1))) const unsigned int* gptr_t;
typedef __attribute__((address_space(3)))       unsigned int* lptr_t;

// pack two fp32 -> two bf16 (truncation; numerics identical to prior passing versions)
__device__ __forceinline__ unsigned pk_bf16(float lo, float hi) {
    return (__float_as_uint(lo) >> 16) | (__float_as_uint(hi) & 0xffff0000u);
}

// async global->LDS, 16B per lane; LDS dest = wave-uniform base + lane*16
__device__ __forceinline__ void gload_lds16(const void* g, void* l) {
    __builtin_amdgcn_global_load_lds((gptr_t)g, (lptr_t)l, 16, 0, 0);
}

// ------ Kernel A: copy A+I to out[:,256:], col sums -> d, bf16 A -> aP ---------
__global__ __launch_bounds__(256) void kcopy(const float* __restrict__ in,
                                             float* __restrict__ out,
                                             float* __restrict__ d,
                                             unsigned short* __restrict__ aP) {
    const int t  = threadIdx.x;
    const int j0 = blockIdx.x * 1024;   // 8 col tiles of 1024
    const int i0 = blockIdx.y * 32;     // 256 row tiles of 32
    const int jc = j0 + 4 * t;
    const float*    src = in  + (size_t)i0 * INW  + AOFF + jc;
    float*          dst = out + (size_t)i0 * OUTW + DO   + jc;
    unsigned short* ap  = aP  + (size_t)i0 * NSMP + jc;
    f32x4 cs = {0.f, 0.f, 0.f, 0.f};
#pragma unroll 8
    for (int r = 0; r < 32; ++r) {
        f32x4 v = __builtin_nontemporal_load((const f32x4*)(src + (size_t)r * INW));
        uint2 pb;                                     // raw A (no +I) in bf16 for kmm
        pb.x = pk_bf16(v[0], v[1]);
        pb.y = pk_bf16(v[2], v[3]);
        *(uint2*)(ap + (size_t)r * NSMP) = pb;        // normal store: want aP in L3
        int di = (i0 + r) - j0;                       // diagonal col within tile
        if ((di >> 2) == t) {
            int s = di & 3;
            v[0] += (s == 0); v[1] += (s == 1); v[2] += (s == 2); v[3] += (s == 3);
        }
        cs += v;
        __builtin_nontemporal_store(v, (f32x4*)(dst + (size_t)r * OUTW));
    }
    atomicAdd(&d[jc + 0], cs[0]);
    atomicAdd(&d[jc + 1], cs[1]);
    atomicAdd(&d[jc + 2], cs[2]);
    atomicAdd(&d[jc + 3], cs[3]);
}

// ------- Kernel B: support = X@W, write s' packed k-major: sP[oct=k/8][col][k%8] ----
__global__ __launch_bounds__(256) void ksupport(const float* __restrict__ in,
                                                const float* __restrict__ w,
                                                const float* __restrict__ d,
                                                float* __restrict__ dinv,
                                                unsigned short* __restrict__ sP) {
    const int c  = threadIdx.x;          // output column 0..255
    const int r0 = blockIdx.x * 8;       // 8 support-rows per block = one k-octet
    const float* X = in + (size_t)r0 * INW;   // X = input[:, :512]
    float acc[8] = {0.f, 0.f, 0.f, 0.f, 0.f, 0.f, 0.f, 0.f};
#pragma unroll 4
    for (int k = 0; k < 512; ++k) {
        float wv = w[(size_t)k * DO + c];
#pragma unroll
        for (int r = 0; r < 8; ++r)
            acc[r] = fmaf(X[(size_t)r * INW + k], wv, acc[r]);  // X load wave-uniform -> s_load
    }
    union { unsigned short h[8]; uint4 u; } pk;
#pragma unroll
    for (int r = 0; r < 8; ++r) {
        float dv = rsqrtf(d[r0 + r]);
        unsigned ub = __float_as_uint(acc[r] * dv);
        ub += 0x7fffu + ((ub >> 16) & 1u);            // RNE to bf16
        pk.h[r] = (unsigned short)(ub >> 16);
    }
    *(uint4*)(sP + (size_t)(r0 >> 3) * (DO * 8) + (size_t)c * 8) = pk.u;
    if (c < 8) dinv[r0 + c] = rsqrtf(d[r0 + c]);
}

// ---------------- Kernel C: out[:, :256] = dinv_i * (A0 @ s' + s'_i) -----------
// BM=64, BN=128, 8 waves (512 thr): wave w -> row-half wm=w>>2, col-strip wn=w&3.
// 256 blocks = 1 block/CU = 2 waves/SIMD (same occupancy as r5's 2x4-wave).
// B per block unchanged (2MB) but half the blocks -> B L2 traffic 1GB -> 512MB.
// Schedule identical to r5: per wave 5 VMEM/step (1 A-stage + 4 B), vmcnt(5)+barrier.
// wm=0/1 wave pairs duplicate B loads -> L1-absorbed (16KB step set << 32KB L1).
__global__ __launch_bounds__(512, 2) void kmm(const unsigned short* __restrict__ aP,
                                              const unsigned short* __restrict__ sP,
                                              const float* __restrict__ dinv,
                                              float* __restrict__ out) {
    __shared__ __align__(16) unsigned short lA[3][64 * 64];   // 3 x 8 KB = 24 KB

    const int b  = blockIdx.x;
    // XCD-pair swizzle: blocks b and b+8 (same rg, ch=0/1) land on the same XCD (b%8)
    const int rg = ((b >> 4) << 3) + (b & 7);   // 0..127 row group (64 rows each)
    const int ch = (b >> 3) & 1;                // column half
    const int tid = threadIdx.x;
    const int w = tid >> 6, lane = tid & 63;    // w = 0..7
    const int m = lane & 31, q = lane >> 5;
    const int wm = w >> 2, wn = w & 3;          // row-half / col-strip of this wave
    const int i0 = rg * 64;
    const int cc = ch * 128 + wn * 32 + m;

    // A stage: wave w stages rows w*8..w*8+7 of the 64-row tile; lane -> (row=l>>3,
    // slot=l&7); source pre-swizzled (slot g holds granule g^(row&7)) for swizzled reads
    const int srow = lane >> 3;
    const int sg   = lane & 7;
    const unsigned short* aSrc = aP + (size_t)(i0 + w * 8 + srow) * NSMP
                                    + 8 * (sg ^ (srow & 7));
    const unsigned short* bB   = sP + (size_t)q * 2048 + (size_t)cc * 8;

    floatx16 acc;
#pragma unroll
    for (int z = 0; z < 16; ++z) acc[z] = 0.f;

    uint4 Ba0, Ba1, Ba2, Ba3, Bb0, Bb1, Bb2, Bb3;

#define STAGE_A(nb, s) gload_lds16(aSrc + (size_t)(s) * 64, &lA[nb][w * 512])
#define LOAD_B(P, s) do {                                              \
        P##0 = *(const uint4*)(bB + (size_t)((s) * 8 + 0) * 2048);     \
        P##1 = *(const uint4*)(bB + (size_t)((s) * 8 + 2) * 2048);     \
        P##2 = *(const uint4*)(bB + (size_t)((s) * 8 + 4) * 2048);     \
        P##3 = *(const uint4*)(bB + (size_t)((s) * 8 + 6) * 2048);     \
    } while (0)
#define MFMA_KS(cur, Breg, ks) do {                                    \
        union { uint4 u; short8 s8; } fb_; fb_.u = Breg;               \
        const short8 af_ = *(const short8*)(                           \
            &lA[cur][(wm * 32 + m) * 64 + ((((ks) * 2 + q) ^ (m & 7)) * 8)]); \
        acc = __builtin_amdgcn_mfma_f32_32x32x16_bf16(af_, fb_.s8, acc, 0, 0, 0); \
    } while (0)
#define COMPUTE(cur, P) do {                                           \
        MFMA_KS(cur, P##0, 0); MFMA_KS(cur, P##1, 1);                  \
        MFMA_KS(cur, P##2, 2); MFMA_KS(cur, P##3, 3);                  \
    } while (0)

    STAGE_A(0, 0);  LOAD_B(Ba, 0);
    STAGE_A(1, 1);  LOAD_B(Bb, 1);

    int rd = 0, wr = 2;
    for (int s = 0; s < 128; s += 2) {
        asm volatile("s_waitcnt vmcnt(5)" ::: "memory");
        __builtin_amdgcn_s_barrier();
        STAGE_A(wr, (s + 2) & 127);          // &127 tail strays hit a dead buffer: safe
        __builtin_amdgcn_s_setprio(1);
        COMPUTE(rd, Ba);                     // WAR on Ba keeps reload below the MFMAs
        __builtin_amdgcn_s_setprio(0);
        LOAD_B(Ba, (s + 2) & 127);
        rd = (rd == 2) ? 0 : rd + 1;
        wr = (wr == 2) ? 0 : wr + 1;

        asm volatile("s_waitcnt vmcnt(5)" ::: "memory");
        __builtin_amdgcn_s_barrier();
        STAGE_A(wr, (s + 3) & 127);
        __builtin_amdgcn_s_setprio(1);
        COMPUTE(rd, Bb);
        __builtin_amdgcn_s_setprio(0);
        LOAD_B(Bb, (s + 3) & 127);
        rd = (rd == 2) ? 0 : rd + 1;
        wr = (wr == 2) ? 0 : wr + 1;
    }

#undef STAGE_A
#undef LOAD_B
#undef MFMA_KS
#undef COMPUTE

    // epilogue: D row = (reg&3) + 8*(reg>>2) + 4*q, col = lane&31 (HW-verified layout)
    const int r0 = i0 + wm * 32;
#pragma unroll
    for (int g = 0; g < 4; ++g) {
        const ushort4 s4 = *(const ushort4*)(sP + (size_t)(r0 / 8 + g) * (DO * 8)
                                                + (size_t)cc * 8 + 4 * q);
        unsigned short sv[4] = {s4.x, s4.y, s4.z, s4.w};
#pragma unroll
        for (int rr = 0; rr < 4; ++rr) {
            const int row = r0 + 8 * g + 4 * q + rr;
            const float idt = __uint_as_float(((unsigned)sv[rr]) << 16);  // +I contribution
            out[(size_t)row * OUTW + cc] = (acc[g * 4 + rr] + idt) * dinv[row];
        }
    }
}

extern "C" void kernel_launch(void* const* d_in, const int* in_sizes, int n_in,
                              void* d_out, int out_size, void* d_ws, size_t ws_size,
                              hipStream_t stream) {
    (void)in_sizes; (void)n_in; (void)out_size; (void)ws_size;
    const float* in = (const float*)d_in[0];
    const float* w  = (const float*)d_in[1];
    float* out  = (float*)d_out;
    float* d    = (float*)d_ws;                            // 8192 f32 column sums
    float* dinv = d + NSMP;                                // 8192 f32
    unsigned short* sP = (unsigned short*)(d + 2 * NSMP);  // 1024 x 256 x 8 bf16 (4 MB)
    unsigned short* aP = sP + (size_t)1024 * DO * 8;       // 8192 x 8192 bf16 (128 MB)

    hipMemsetAsync(d, 0, NSMP * sizeof(float), stream);
    kcopy<<<dim3(8, 256), 256, 0, stream>>>(in, out, d, aP);
    ksupport<<<1024, 256, 0, stream>>>(in, w, d, dinv, sP);
    kmm<<<256, 512, 0, stream>>>(aP, sP, dinv, out);
}

// Round 7
// 611.197 us; speedup vs baseline: 1.0148x; 1.0148x over previous
//
#include <hip/hip_runtime.h>

#define NSMP 8192
#define INW  8712   // input row stride (floats)
#define OUTW 8448   // output row stride (floats)
#define AOFF 512    // column offset of A block inside input
#define DO   256    // DOUT

typedef __attribute__((ext_vector_type(4)))  float f32x4;
typedef __attribute__((ext_vector_type(8)))  short short8;
typedef __attribute__((ext_vector_type(16))) float floatx16;

typedef __attribute__((address_space(1))) const unsigned int* gptr_t;
typedef __attribute__((address_space(3)))       unsigned int* lptr_t;

// pack two fp32 -> two bf16 (truncation; numerics identical to prior passing versions)
__device__ __forceinline__ unsigned pk_bf16(float lo, float hi) {
    return (__float_as_uint(lo) >> 16) | (__float_as_uint(hi) & 0xffff0000u);
}

// async global->LDS, 16B per lane; LDS dest = wave-uniform base + lane*16
__device__ __forceinline__ void gload_lds16(const void* g, void* l) {
    __builtin_amdgcn_global_load_lds((gptr_t)g, (lptr_t)l, 16, 0, 0);
}

// ------ Kernel A: copy A+I to out[:,256:], col sums -> d, bf16 A -> aP ---------
__global__ __launch_bounds__(256) void kcopy(const float* __restrict__ in,
                                             float* __restrict__ out,
                                             float* __restrict__ d,
                                             unsigned short* __restrict__ aP) {
    const int t  = threadIdx.x;
    const int j0 = blockIdx.x * 1024;   // 8 col tiles of 1024
    const int i0 = blockIdx.y * 32;     // 256 row tiles of 32
    const int jc = j0 + 4 * t;
    const float*    src = in  + (size_t)i0 * INW  + AOFF + jc;
    float*          dst = out + (size_t)i0 * OUTW + DO   + jc;
    unsigned short* ap  = aP  + (size_t)i0 * NSMP + jc;
    f32x4 cs = {0.f, 0.f, 0.f, 0.f};
#pragma unroll 8
    for (int r = 0; r < 32; ++r) {
        f32x4 v = __builtin_nontemporal_load((const f32x4*)(src + (size_t)r * INW));
        uint2 pb;                                     // raw A (no +I) in bf16 for kmm
        pb.x = pk_bf16(v[0], v[1]);
        pb.y = pk_bf16(v[2], v[3]);
        *(uint2*)(ap + (size_t)r * NSMP) = pb;        // normal store: want aP in L3
        int di = (i0 + r) - j0;                       // diagonal col within tile
        if ((di >> 2) == t) {
            int s = di & 3;
            v[0] += (s == 0); v[1] += (s == 1); v[2] += (s == 2); v[3] += (s == 3);
        }
        cs += v;
        __builtin_nontemporal_store(v, (f32x4*)(dst + (size_t)r * OUTW));
    }
    atomicAdd(&d[jc + 0], cs[0]);
    atomicAdd(&d[jc + 1], cs[1]);
    atomicAdd(&d[jc + 2], cs[2]);
    atomicAdd(&d[jc + 3], cs[3]);
}

// ------- Kernel B: support = X@W, write s' packed k-major: sP[oct=k/8][col][k%8] ----
__global__ __launch_bounds__(256) void ksupport(const float* __restrict__ in,
                                                const float* __restrict__ w,
                                                const float* __restrict__ d,
                                                float* __restrict__ dinv,
                                                unsigned short* __restrict__ sP) {
    const int c  = threadIdx.x;          // output column 0..255
    const int r0 = blockIdx.x * 8;       // 8 support-rows per block = one k-octet
    const float* X = in + (size_t)r0 * INW;   // X = input[:, :512]
    float acc[8] = {0.f, 0.f, 0.f, 0.f, 0.f, 0.f, 0.f, 0.f};
#pragma unroll 4
    for (int k = 0; k < 512; ++k) {
        float wv = w[(size_t)k * DO + c];
#pragma unroll
        for (int r = 0; r < 8; ++r)
            acc[r] = fmaf(X[(size_t)r * INW + k], wv, acc[r]);  // X load wave-uniform -> s_load
    }
    union { unsigned short h[8]; uint4 u; } pk;
#pragma unroll
    for (int r = 0; r < 8; ++r) {
        float dv = rsqrtf(d[r0 + r]);
        unsigned ub = __float_as_uint(acc[r] * dv);
        ub += 0x7fffu + ((ub >> 16) & 1u);            // RNE to bf16
        pk.h[r] = (unsigned short)(ub >> 16);
    }
    *(uint4*)(sP + (size_t)(r0 >> 3) * (DO * 8) + (size_t)c * 8) = pk.u;
    if (c < 8) dinv[r0 + c] = rsqrtf(d[r0 + c]);
}

// ---------------- Kernel C: partial P[kh] = A[:, kh-half] @ s'[kh-half] -------
// r5 structure (best measured) + K-split: 1024 blocks = 512 tiles x 2 k-halves,
// 64 steps each -> 4096 waves = 4 waves/SIMD (2x occupancy; the r6 A/B showed
// kmm is latency-bound, not B-BW-bound). Schedule unchanged: 5 VMEM/wave/step,
// wait vmcnt(5) then s_barrier (2-step-old loads retired across all waves).
__global__ __launch_bounds__(256, 4) void kmm(const unsigned short* __restrict__ aP,
                                              const unsigned short* __restrict__ sP,
                                              float* __restrict__ P) {
    __shared__ __align__(16) unsigned short lA[3][32 * 64];   // 12 KB total

    const int bl = blockIdx.x;
    const int kh = bl >> 9;                     // k-half 0/1
    const int b  = bl & 511;                    // tile id
    // XCD-pair swizzle: b and b+8 (ch pair) and b+512 (kh pair) share XCD (bl%8)
    const int rg = ((b >> 4) << 3) + (b & 7);   // 0..255 row group
    const int ch = (b >> 3) & 1;                // column half
    const int tid = threadIdx.x;
    const int w = tid >> 6, lane = tid & 63;
    const int m = lane & 31, q = lane >> 5;
    const int i0 = rg * 32;
    const int cc = ch * 128 + w * 32 + m;
    const int t0 = kh * 64;                     // first global k-step of this half

    // A stage: wave w stages rows w*8..w*8+7; lane -> (row = l>>3, slot = l&7);
    // global source pre-swizzled (slot g holds granule g^(row&7)) -> swizzled ds_read
    const int srow = lane >> 3;
    const int sg   = lane & 7;
    const unsigned short* aSrc = aP + (size_t)(i0 + w * 8 + srow) * NSMP
                                    + 8 * (sg ^ (srow & 7));
    const unsigned short* bB   = sP + (size_t)q * 2048 + (size_t)cc * 8;

    floatx16 acc;
#pragma unroll
    for (int z = 0; z < 16; ++z) acc[z] = 0.f;

    uint4 Ba0, Ba1, Ba2, Ba3, Bb0, Bb1, Bb2, Bb3;

#define STAGE_A(nb, t) gload_lds16(aSrc + (size_t)(t) * 64, &lA[nb][w * 512])
#define LOAD_B(Q, t) do {                                              \
        Q##0 = *(const uint4*)(bB + (size_t)((t) * 8 + 0) * 2048);     \
        Q##1 = *(const uint4*)(bB + (size_t)((t) * 8 + 2) * 2048);     \
        Q##2 = *(const uint4*)(bB + (size_t)((t) * 8 + 4) * 2048);     \
        Q##3 = *(const uint4*)(bB + (size_t)((t) * 8 + 6) * 2048);     \
    } while (0)
#define MFMA_KS(cur, Breg, ks) do {                                    \
        union { uint4 u; short8 s8; } fb_; fb_.u = Breg;               \
        const short8 af_ = *(const short8*)(                           \
            &lA[cur][m * 64 + ((((ks) * 2 + q) ^ (m & 7)) * 8)]);      \
        acc = __builtin_amdgcn_mfma_f32_32x32x16_bf16(af_, fb_.s8, acc, 0, 0, 0); \
    } while (0)
#define COMPUTE(cur, Q) do {                                           \
        MFMA_KS(cur, Q##0, 0); MFMA_KS(cur, Q##1, 1);                  \
        MFMA_KS(cur, Q##2, 2); MFMA_KS(cur, Q##3, 3);                  \
    } while (0)

    STAGE_A(0, t0);      LOAD_B(Ba, t0);
    STAGE_A(1, t0 + 1);  LOAD_B(Bb, t0 + 1);

    int rd = 0, wr = 2;
    for (int s = 0; s < 64; s += 2) {
        asm volatile("s_waitcnt vmcnt(5)" ::: "memory");
        __builtin_amdgcn_s_barrier();
        STAGE_A(wr, t0 + ((s + 2) & 63));    // &63 tail strays hit a dead buffer: safe
        __builtin_amdgcn_s_setprio(1);
        COMPUTE(rd, Ba);                     // WAR on Ba keeps reload below the MFMAs
        __builtin_amdgcn_s_setprio(0);
        LOAD_B(Ba, t0 + ((s + 2) & 63));
        rd = (rd == 2) ? 0 : rd + 1;
        wr = (wr == 2) ? 0 : wr + 1;

        asm volatile("s_waitcnt vmcnt(5)" ::: "memory");
        __builtin_amdgcn_s_barrier();
        STAGE_A(wr, t0 + ((s + 3) & 63));
        __builtin_amdgcn_s_setprio(1);
        COMPUTE(rd, Bb);
        __builtin_amdgcn_s_setprio(0);
        LOAD_B(Bb, t0 + ((s + 3) & 63));
        rd = (rd == 2) ? 0 : rd + 1;
        wr = (wr == 2) ? 0 : wr + 1;
    }

#undef STAGE_A
#undef LOAD_B
#undef MFMA_KS
#undef COMPUTE

    // write raw fp32 partial; epilogue (idt, dinv) moves to kreduce
    // D row = (reg&3) + 8*(reg>>2) + 4*q, col = lane&31 (HW-verified layout)
    float* Pb = P + (size_t)kh * NSMP * DO;
#pragma unroll
    for (int g = 0; g < 4; ++g) {
#pragma unroll
        for (int rr = 0; rr < 4; ++rr) {
            const int row = i0 + 8 * g + 4 * q + rr;
            Pb[(size_t)row * DO + cc] = acc[g * 4 + rr];
        }
    }
}

// -------- Kernel D: out[:, :256] = (P0 + P1 + idt) * dinv -------------------
__global__ __launch_bounds__(256) void kreduce(const float* __restrict__ P,
                                               const unsigned short* __restrict__ sP,
                                               const float* __restrict__ dinv,
                                               float* __restrict__ out) {
    const int c = threadIdx.x;
    const int r0 = blockIdx.x * 4;
#pragma unroll
    for (int rr = 0; rr < 4; ++rr) {
        const int row = r0 + rr;
        const float p0 = P[(size_t)row * DO + c];
        const float p1 = P[(size_t)(NSMP + row) * DO + c];
        const unsigned short sv = sP[(size_t)(row >> 3) * (DO * 8)
                                     + (size_t)c * 8 + (row & 7)];
        const float idt = __uint_as_float(((unsigned)sv) << 16);
        out[(size_t)row * OUTW + c] = (p0 + p1 + idt) * dinv[row];
    }
}

extern "C" void kernel_launch(void* const* d_in, const int* in_sizes, int n_in,
                              void* d_out, int out_size, void* d_ws, size_t ws_size,
                              hipStream_t stream) {
    (void)in_sizes; (void)n_in; (void)out_size; (void)ws_size;
    const float* in = (const float*)d_in[0];
    const float* w  = (const float*)d_in[1];
    float* out  = (float*)d_out;
    float* d    = (float*)d_ws;                            // 8192 f32 column sums
    float* dinv = d + NSMP;                                // 8192 f32
    unsigned short* sP = (unsigned short*)(d + 2 * NSMP);  // 1024 x 256 x 8 bf16 (4 MB)
    unsigned short* aP = sP + (size_t)1024 * DO * 8;       // 8192 x 8192 bf16 (128 MB)
    float* P = (float*)(aP + (size_t)NSMP * NSMP);         // 2 x 8192 x 256 f32 (16 MB)

    hipMemsetAsync(d, 0, NSMP * sizeof(float), stream);
    kcopy<<<dim3(8, 256), 256, 0, stream>>>(in, out, d, aP);
    ksupport<<<1024, 256, 0, stream>>>(in, w, d, dinv, sP);
    kmm<<<1024, 256, 0, stream>>>(aP, sP, P);
    kreduce<<<2048, 256, 0, stream>>>(P, sP, dinv, out);
}